// Round 1
// baseline (3092.513 us; speedup 1.0000x reference)
//
#include <hip/hip_runtime.h>
#include <math.h>

// -----------------------------------------------------------------------------
// DFSPH divergence-solve fused kernel.
// Inputs (d_in order):
//  0 fluidArea            [N]   f32
//  1 fluidActualArea      [N]   f32
//  2 fluidRestDensity     [N]   f32
//  3 fluidDensity         [N]   f32
//  4 fluidPressure2       [N]   f32
//  5 fluidPredictedVelocity [N,2] f32
//  6 fluidPredAccel       [N,2] f32
//  7 fluidRadialDistances [E]   f32
//  8 fluidDistances       [E,2] f32
//  9 fluidNeighbors       [2,E] i32
// 10 support              [1]   f32
// 11 dt                   [1]   f32
// Output: [N,5] f32 rows = {alpha, accelTerm.x, accelTerm.y, source, kernelSum}
// Workspace layout: pre float4[N] at 0; acc float[N*8] after.
// -----------------------------------------------------------------------------

__global__ void pre_kernel(const float* __restrict__ area,
                           const float* __restrict__ actualArea,
                           const float* __restrict__ restDensity,
                           const float* __restrict__ density,
                           const float* __restrict__ pressure2,
                           float4* __restrict__ pre,
                           float* __restrict__ acc,
                           int n) {
    int t = blockIdx.x * blockDim.x + threadIdx.x;
    if (t >= n) return;
    float m  = area[t] * restDensity[t];
    float dr = density[t] * restDensity[t];
    float p  = pressure2[t] / (dr * dr);
    float aa = actualArea[t];
    pre[t] = make_float4(p, m, aa * aa / m, aa);
    float* a = acc + (size_t)t * 8;
#pragma unroll
    for (int k = 0; k < 8; ++k) a[k] = 0.f;
}

__global__ void edge_kernel(const int*    __restrict__ nbr,    // [2,E]
                            const float*  __restrict__ rad,    // [E]
                            const float2* __restrict__ dirs,   // [E]
                            const float4* __restrict__ pre,    // [N] {p,mass,aa2,aa}
                            const float2* __restrict__ vel,    // [N]
                            const float2* __restrict__ accel,  // [N]
                            const float*  __restrict__ supp,   // [1]
                            const float*  __restrict__ dtp,    // [1]
                            float*        __restrict__ acc,    // [N,8]
                            int E) {
    int e = blockIdx.x * blockDim.x + threadIdx.x;
    if (e >= E) return;
    float h  = supp[0];
    float dt = dtp[0];
    // 20 * (7/pi) / h^3  -- Wendland C2 2D gradient magnitude coefficient
    float kc = 20.0f * (7.0f / 3.14159265358979323846f) / (h * h * h);

    int i = nbr[e];
    int j = nbr[E + e];
    float  q = rad[e];
    float2 d = dirs[e];
    float om  = 1.0f - q;
    float mag = kc * q * om * om * om;
    float gx = -d.x * mag;
    float gy = -d.y * mag;
    float g2 = gx * gx + gy * gy;

    float4 pj = pre[j];
    float4 pi = pre[i];
    float aaj = pj.w;
    float pp  = -pj.y * (pi.x + pj.x);   // facA * (p_i + p_j)

    float2 vi = vel[i],   vj = vel[j];
    float2 ai = accel[i], aj = accel[j];
    float vdotg = (vi.x - vj.x) * gx + (vi.y - vj.y) * gy;
    float adotg = (ai.x - aj.x) * gx + (ai.y - aj.y) * gy;

    float* base = acc + (size_t)i * 8;
    atomicAdd(base + 0, aaj * gx);            // kSum1.x
    atomicAdd(base + 1, aaj * gy);            // kSum1.y
    atomicAdd(base + 2, pj.z * g2);           // kSum2
    atomicAdd(base + 3, pp * gx);             // accelTerm.x
    atomicAdd(base + 4, pp * gy);             // accelTerm.y
    atomicAdd(base + 5, -dt * aaj * vdotg);   // source
    atomicAdd(base + 6, dt * dt * aaj * adotg); // kernelSum
}

__global__ void fin_kernel(const float* __restrict__ area,
                           const float* __restrict__ actualArea,
                           const float* __restrict__ restDensity,
                           const float* __restrict__ dtp,
                           const float* __restrict__ acc,
                           float* __restrict__ out,
                           int n) {
    int t = blockIdx.x * blockDim.x + threadIdx.x;
    if (t >= n) return;
    float dt   = dtp[0];
    float fac  = -dt * dt * actualArea[t];
    float mass = area[t] * restDensity[t];
    const float* a = acc + (size_t)t * 8;
    float alpha = fac / mass * (a[0] * a[0] + a[1] * a[1]) + fac * a[2];
    float* o = out + (size_t)t * 5;
    o[0] = alpha;
    o[1] = a[3];
    o[2] = a[4];
    o[3] = a[5];
    o[4] = a[6];
}

extern "C" void kernel_launch(void* const* d_in, const int* in_sizes, int n_in,
                              void* d_out, int out_size, void* d_ws, size_t ws_size,
                              hipStream_t stream) {
    const float* area        = (const float*)d_in[0];
    const float* actualArea  = (const float*)d_in[1];
    const float* restDensity = (const float*)d_in[2];
    const float* density     = (const float*)d_in[3];
    const float* pressure2   = (const float*)d_in[4];
    const float2* vel        = (const float2*)d_in[5];
    const float2* accel      = (const float2*)d_in[6];
    const float* rad         = (const float*)d_in[7];
    const float2* dirs       = (const float2*)d_in[8];
    const int*   nbr         = (const int*)d_in[9];
    const float* supp        = (const float*)d_in[10];
    const float* dtp         = (const float*)d_in[11];
    float* out = (float*)d_out;

    int N = in_sizes[0];
    int E = in_sizes[7];

    float4* pre = (float4*)d_ws;
    float*  acc = (float*)((char*)d_ws + (size_t)N * sizeof(float4));

    int bs = 256;
    pre_kernel<<<(N + bs - 1) / bs, bs, 0, stream>>>(
        area, actualArea, restDensity, density, pressure2, pre, acc, N);
    edge_kernel<<<(E + bs - 1) / bs, bs, 0, stream>>>(
        nbr, rad, dirs, pre, vel, accel, supp, dtp, acc, E);
    fin_kernel<<<(N + bs - 1) / bs, bs, 0, stream>>>(
        area, actualArea, restDensity, dtp, acc, out, N);
}

// Round 2
// 2175.200 us; speedup vs baseline: 1.4217x; 1.4217x over previous
//
#include <hip/hip_runtime.h>
#include <math.h>

// -----------------------------------------------------------------------------
// DFSPH divergence-solve, binning formulation.
// Buckets: particle i -> bucket (i >> 8); each bucket owns 256 particles.
// Pass 1 (pre):   per-particle precompute {p, mass, aa^2/mass, aa}; zero acc+cursors.
// Pass 2 (bin):   per-edge contributions -> 32B payload into its bucket
//                 (slot claimed via int atomic on 4KB cursor array).
// Pass 3 (reduce):per-bucket LDS accumulation (stride 9 to avoid bank conflicts),
//                 added into global acc[N,8].
// Pass 4 (fin):   alpha + output [N,5].
// Workspace: [cursors (buckets*16 ints)] [pre float4[N]] [acc float[N*8]] [payload]
// Fallback: if ws too small even for 16 chunks, use direct-atomic path (round-1).
// -----------------------------------------------------------------------------

static inline size_t align256(size_t x) { return (x + 255) & ~(size_t)255; }

__global__ void pre_kernel(const float* __restrict__ area,
                           const float* __restrict__ actualArea,
                           const float* __restrict__ restDensity,
                           const float* __restrict__ density,
                           const float* __restrict__ pressure2,
                           float4* __restrict__ pre,
                           float* __restrict__ acc,
                           int* __restrict__ cursor, int ncursor,
                           int n) {
    int t = blockIdx.x * blockDim.x + threadIdx.x;
    if (t < ncursor) cursor[t] = 0;
    if (t >= n) return;
    float m  = area[t] * restDensity[t];
    float dr = density[t] * restDensity[t];
    float p  = pressure2[t] / (dr * dr);
    float aa = actualArea[t];
    pre[t] = make_float4(p, m, aa * aa / m, aa);
    float* a = acc + (size_t)t * 8;
#pragma unroll
    for (int k = 0; k < 8; ++k) a[k] = 0.f;
}

__device__ __forceinline__ void edge_math(
    const int* __restrict__ nbr, const float* __restrict__ rad,
    const float2* __restrict__ dirs, const float4* __restrict__ pre,
    const float2* __restrict__ vel, const float2* __restrict__ accel,
    float h, float dt, int e, int E,
    int& i_out, float& c0, float& c1, float& c2, float& c3, float& c4,
    float& c5, float& c6) {
    float kc = 20.0f * (7.0f / 3.14159265358979323846f) / (h * h * h);
    int i = nbr[e];
    int j = nbr[E + e];
    float  q = rad[e];
    float2 d = dirs[e];
    float om  = 1.0f - q;
    float mag = kc * q * om * om * om;
    float gx = -d.x * mag;
    float gy = -d.y * mag;
    float g2 = gx * gx + gy * gy;

    float4 pj = pre[j];
    float4 pi = pre[i];
    float aaj = pj.w;
    float pp  = -pj.y * (pi.x + pj.x);   // facA * (p_i + p_j)

    float2 vi = vel[i],   vj = vel[j];
    float2 ai = accel[i], aj = accel[j];
    float vdotg = (vi.x - vj.x) * gx + (vi.y - vj.y) * gy;
    float adotg = (ai.x - aj.x) * gx + (ai.y - aj.y) * gy;

    i_out = i;
    c0 = aaj * gx;              // kSum1.x
    c1 = aaj * gy;              // kSum1.y
    c2 = pj.z * g2;             // kSum2
    c3 = pp * gx;               // accelTerm.x
    c4 = pp * gy;               // accelTerm.y
    c5 = -dt * aaj * vdotg;     // source
    c6 = dt * dt * aaj * adotg; // kernelSum
}

__global__ void bin_kernel(const int*    __restrict__ nbr,
                           const float*  __restrict__ rad,
                           const float2* __restrict__ dirs,
                           const float4* __restrict__ pre,
                           const float2* __restrict__ vel,
                           const float2* __restrict__ accel,
                           const float*  __restrict__ supp,
                           const float*  __restrict__ dtp,
                           int*          __restrict__ cursor,
                           float4*       __restrict__ payload,
                           int cap, int estart, int eend, int E) {
    int e = estart + blockIdx.x * blockDim.x + threadIdx.x;
    if (e >= eend) return;
    int i; float c0, c1, c2, c3, c4, c5, c6;
    edge_math(nbr, rad, dirs, pre, vel, accel, supp[0], dtp[0], e, E,
              i, c0, c1, c2, c3, c4, c5, c6);
    int b = i >> 8;
    int slot = atomicAdd(cursor + b, 1);
    if (slot >= cap) return;  // statistically impossible (8-sigma margin)
    size_t idx = ((size_t)b * cap + slot) * 2;
    payload[idx]     = make_float4(c0, c1, c2, c3);
    payload[idx + 1] = make_float4(c4, c5, c6, __int_as_float(i));
}

__global__ __launch_bounds__(256) void reduce_kernel(
    const float4* __restrict__ payload,
    const int*    __restrict__ cursor, int cap,
    float*        __restrict__ acc, int n) {
    __shared__ float lacc[256 * 9];  // stride 9: avoids 4-bank clustering
    int b = blockIdx.x, tid = threadIdx.x;
    for (int k = tid; k < 256 * 9; k += 256) lacc[k] = 0.f;
    __syncthreads();
    int cnt = cursor[b];
    if (cnt > cap) cnt = cap;
    size_t base = (size_t)b * cap * 2;
    for (int t = tid; t < cnt; t += 256) {
        float4 e0 = payload[base + (size_t)t * 2];
        float4 e1 = payload[base + (size_t)t * 2 + 1];
        int li = (__float_as_int(e1.w) & 255) * 9;
        atomicAdd(&lacc[li + 0], e0.x);
        atomicAdd(&lacc[li + 1], e0.y);
        atomicAdd(&lacc[li + 2], e0.z);
        atomicAdd(&lacc[li + 3], e0.w);
        atomicAdd(&lacc[li + 4], e1.x);
        atomicAdd(&lacc[li + 5], e1.y);
        atomicAdd(&lacc[li + 6], e1.z);
    }
    __syncthreads();
    int p = b * 256 + tid;
    if (p < n) {
        float* a = acc + (size_t)p * 8;
        const float* l = &lacc[tid * 9];
#pragma unroll
        for (int k = 0; k < 7; ++k) a[k] += l[k];
    }
}

// ---- fallback path: direct global atomics (round-1 structure) ----
__global__ void edge_kernel(const int*    __restrict__ nbr,
                            const float*  __restrict__ rad,
                            const float2* __restrict__ dirs,
                            const float4* __restrict__ pre,
                            const float2* __restrict__ vel,
                            const float2* __restrict__ accel,
                            const float*  __restrict__ supp,
                            const float*  __restrict__ dtp,
                            float*        __restrict__ acc,
                            int E) {
    int e = blockIdx.x * blockDim.x + threadIdx.x;
    if (e >= E) return;
    int i; float c0, c1, c2, c3, c4, c5, c6;
    edge_math(nbr, rad, dirs, pre, vel, accel, supp[0], dtp[0], e, E,
              i, c0, c1, c2, c3, c4, c5, c6);
    float* base = acc + (size_t)i * 8;
    atomicAdd(base + 0, c0);
    atomicAdd(base + 1, c1);
    atomicAdd(base + 2, c2);
    atomicAdd(base + 3, c3);
    atomicAdd(base + 4, c4);
    atomicAdd(base + 5, c5);
    atomicAdd(base + 6, c6);
}

__global__ void fin_kernel(const float* __restrict__ area,
                           const float* __restrict__ actualArea,
                           const float* __restrict__ restDensity,
                           const float* __restrict__ dtp,
                           const float* __restrict__ acc,
                           float* __restrict__ out,
                           int n) {
    int t = blockIdx.x * blockDim.x + threadIdx.x;
    if (t >= n) return;
    float dt   = dtp[0];
    float fac  = -dt * dt * actualArea[t];
    float mass = area[t] * restDensity[t];
    const float* a = acc + (size_t)t * 8;
    float alpha = fac / mass * (a[0] * a[0] + a[1] * a[1]) + fac * a[2];
    float* o = out + (size_t)t * 5;
    o[0] = alpha;
    o[1] = a[3];
    o[2] = a[4];
    o[3] = a[5];
    o[4] = a[6];
}

extern "C" void kernel_launch(void* const* d_in, const int* in_sizes, int n_in,
                              void* d_out, int out_size, void* d_ws, size_t ws_size,
                              hipStream_t stream) {
    const float* area        = (const float*)d_in[0];
    const float* actualArea  = (const float*)d_in[1];
    const float* restDensity = (const float*)d_in[2];
    const float* density     = (const float*)d_in[3];
    const float* pressure2   = (const float*)d_in[4];
    const float2* vel        = (const float2*)d_in[5];
    const float2* accel      = (const float2*)d_in[6];
    const float* rad         = (const float*)d_in[7];
    const float2* dirs       = (const float2*)d_in[8];
    const int*   nbr         = (const int*)d_in[9];
    const float* supp        = (const float*)d_in[10];
    const float* dtp         = (const float*)d_in[11];
    float* out = (float*)d_out;

    int N = in_sizes[0];
    int E = in_sizes[7];
    int buckets = (N + 255) >> 8;

    const int MAXCHUNK = 16;
    size_t off_pre     = align256((size_t)buckets * MAXCHUNK * sizeof(int));
    size_t off_acc     = align256(off_pre + (size_t)N * sizeof(float4));
    size_t off_payload = align256(off_acc + (size_t)N * 8 * sizeof(float));

    int* cursor      = (int*)d_ws;
    float4* pre      = (float4*)((char*)d_ws + off_pre);
    float*  acc      = (float*)((char*)d_ws + off_acc);
    float4* payload  = (float4*)((char*)d_ws + off_payload);

    long long avail = (long long)ws_size - (long long)off_payload;
    int nchunk = 0, cap = 0;
    for (int c = 1; c <= MAXCHUNK; c *= 2) {
        int Ec = (E + c - 1) / c;
        double mean = (double)Ec / (double)buckets;
        int need = (int)(mean + 8.0 * sqrt(mean) + 16.0);
        need = (need + 7) & ~7;
        if ((long long)buckets * (long long)need * 32ll <= avail) {
            nchunk = c; cap = need; break;
        }
    }

    int bs = 256;
    int ncursor = (nchunk > 0) ? buckets * nchunk : 0;
    int pre_n = (N > ncursor) ? N : ncursor;
    pre_kernel<<<(pre_n + bs - 1) / bs, bs, 0, stream>>>(
        area, actualArea, restDensity, density, pressure2, pre, acc,
        cursor, ncursor, N);

    if (nchunk > 0) {
        int Ec = (E + nchunk - 1) / nchunk;
        for (int c = 0; c < nchunk; ++c) {
            int es = c * Ec;
            int ee = es + Ec; if (ee > E) ee = E;
            if (es >= ee) break;
            bin_kernel<<<(ee - es + bs - 1) / bs, bs, 0, stream>>>(
                nbr, rad, dirs, pre, vel, accel, supp, dtp,
                cursor + (size_t)c * buckets, payload, cap, es, ee, E);
            reduce_kernel<<<buckets, bs, 0, stream>>>(
                payload, cursor + (size_t)c * buckets, cap, acc, N);
        }
    } else {
        edge_kernel<<<(E + bs - 1) / bs, bs, 0, stream>>>(
            nbr, rad, dirs, pre, vel, accel, supp, dtp, acc, E);
    }

    fin_kernel<<<(N + bs - 1) / bs, bs, 0, stream>>>(
        area, actualArea, restDensity, dtp, acc, out, N);
}

// Round 3
// 750.967 us; speedup vs baseline: 4.1180x; 2.8965x over previous
//
#include <hip/hip_runtime.h>
#include <math.h>

// -----------------------------------------------------------------------------
// DFSPH divergence-solve, block-aggregated binning.
//   buckets: particle i -> bucket (i >> 11), 2048 particles/bucket (N=262144 -> 128)
//   pre:    per-particle 32B struct {p,mass,aa,aa^2/m, vx,vy,ax,ay}; zero cursors.
//   bin:    block of 1024 edges ranks edges per-bucket in LDS, claims ONE global
//           cursor slot-range per (block,bucket) (cursors padded 1/cacheline),
//           writes 32B payload {c0..c6, i} grouped by bucket.
//   reduce: block per (bucket,slice): stream payload slice coalesced, LDS
//           accumulate (2048x7 floats, stride 7), write partial slice (no atomics).
//   fin:    sum 8 slices per particle, compute alpha, write [N,5].
// Fallback (tiny ws): direct global float atomics (round-1 style).
// -----------------------------------------------------------------------------

#define PB        2048
#define PB_SHIFT  11
#define SLICES    8
#define CSTRIDE   16     // ints per cursor -> 64B, one cacheline each
#define EPT       4      // edges per thread in bin

static inline size_t align256(size_t x) { return (x + 255) & ~(size_t)255; }

__global__ __launch_bounds__(256) void pre_kernel(
    const float*  __restrict__ area,
    const float*  __restrict__ actualArea,
    const float*  __restrict__ restDensity,
    const float*  __restrict__ density,
    const float*  __restrict__ pressure2,
    const float2* __restrict__ vel,
    const float2* __restrict__ accel,
    float4* __restrict__ pre2,
    int*    __restrict__ cursor, int ncursor,
    float*  __restrict__ accz, int nacc,
    int n) {
    int t = blockIdx.x * blockDim.x + threadIdx.x;
    if (t < ncursor) cursor[t] = 0;
    for (int k = t; k < nacc; k += gridDim.x * blockDim.x) accz[k] = 0.f;
    if (t >= n) return;
    float m  = area[t] * restDensity[t];
    float dr = density[t] * restDensity[t];
    float p  = pressure2[t] / (dr * dr);
    float aa = actualArea[t];
    float2 v  = vel[t];
    float2 ac = accel[t];
    pre2[2 * (size_t)t]     = make_float4(p, m, aa, aa * aa / m);
    pre2[2 * (size_t)t + 1] = make_float4(v.x, v.y, ac.x, ac.y);
}

__device__ __forceinline__ void edge_math2(
    const int* __restrict__ nbr, const float* __restrict__ rad,
    const float2* __restrict__ dirs, const float4* __restrict__ pre2,
    float h, float dt, int e, int E,
    int& i_out, float4& out0, float4& out1) {
    float kc = 20.0f * (7.0f / 3.14159265358979323846f) / (h * h * h);
    int i = nbr[e];
    int j = nbr[E + e];
    float  q = rad[e];
    float2 d = dirs[e];
    float om  = 1.0f - q;
    float mag = kc * q * om * om * om;
    float gx = -d.x * mag;
    float gy = -d.y * mag;
    float g2 = gx * gx + gy * gy;

    float4 ja = pre2[2 * (size_t)j];      // {p, mass, aa, aa2/m}
    float4 jb = pre2[2 * (size_t)j + 1];  // {vx, vy, ax, ay}
    float4 ia = pre2[2 * (size_t)i];
    float4 ib = pre2[2 * (size_t)i + 1];

    float aaj = ja.z;
    float pp  = -ja.y * (ia.x + ja.x);    // facA * (p_i + p_j)
    float vdotg = (ib.x - jb.x) * gx + (ib.y - jb.y) * gy;
    float adotg = (ib.z - jb.z) * gx + (ib.w - jb.w) * gy;

    i_out = i;
    out0 = make_float4(aaj * gx, aaj * gy, ja.w * g2, pp * gx);
    out1 = make_float4(pp * gy, -dt * aaj * vdotg, dt * dt * aaj * adotg,
                       __int_as_float(i));
}

__global__ __launch_bounds__(256) void bin_kernel(
    const int*    __restrict__ nbr,
    const float*  __restrict__ rad,
    const float2* __restrict__ dirs,
    const float4* __restrict__ pre2,
    const float*  __restrict__ supp,
    const float*  __restrict__ dtp,
    int*          __restrict__ cursor,
    float4*       __restrict__ payload,
    int cap, int nb, int estart, int eend, int E) {
    __shared__ int lcount[512];
    __shared__ int lbase[512];
    int tid = threadIdx.x;
    for (int k = tid; k < nb; k += 256) lcount[k] = 0;
    __syncthreads();
    float h = supp[0], dt = dtp[0];
    int e0 = estart + blockIdx.x * (256 * EPT) + tid;

    int myb[EPT], myr[EPT];
    float4 p0[EPT], p1[EPT];
#pragma unroll
    for (int k = 0; k < EPT; ++k) {
        int e = e0 + k * 256;
        myb[k] = -1;
        if (e < eend) {
            int i;
            edge_math2(nbr, rad, dirs, pre2, h, dt, e, E, i, p0[k], p1[k]);
            int b = i >> PB_SHIFT;
            myb[k] = b;
            myr[k] = atomicAdd(&lcount[b], 1);
        }
    }
    __syncthreads();
    for (int k = tid; k < nb; k += 256) {
        int c = lcount[k];
        lbase[k] = c ? atomicAdd(&cursor[(size_t)k * CSTRIDE], c) : 0;
    }
    __syncthreads();
#pragma unroll
    for (int k = 0; k < EPT; ++k) {
        if (myb[k] >= 0) {
            int slot = lbase[myb[k]] + myr[k];
            if (slot < cap) {   // 8-sigma margin; statistically never taken
                size_t idx = ((size_t)myb[k] * cap + slot) * 2;
                payload[idx]     = p0[k];
                payload[idx + 1] = p1[k];
            }
        }
    }
}

__global__ __launch_bounds__(256) void reduce_kernel(
    const float4* __restrict__ payload,
    const int*    __restrict__ cursor, int cap,
    float*        __restrict__ partials,
    int spc, int soff) {
    __shared__ float lacc[PB * 7];  // 57,344 B; stride 7 (odd) spreads banks
    int b   = blockIdx.x / spc;
    int s   = blockIdx.x % spc;
    int tid = threadIdx.x;
    for (int k = tid; k < PB * 7; k += 256) lacc[k] = 0.f;
    __syncthreads();
    int cnt = cursor[(size_t)b * CSTRIDE];
    if (cnt > cap) cnt = cap;
    int lo = (int)((long long)cnt * s / spc);
    int hi = (int)((long long)cnt * (s + 1) / spc);
    size_t base = (size_t)b * cap * 2;
    for (int t = lo + tid; t < hi; t += 256) {
        float4 e0 = payload[base + 2 * (size_t)t];
        float4 e1 = payload[base + 2 * (size_t)t + 1];
        int li = __float_as_int(e1.w) & (PB - 1);
        float* l = &lacc[li * 7];
        atomicAdd(l + 0, e0.x);
        atomicAdd(l + 1, e0.y);
        atomicAdd(l + 2, e0.z);
        atomicAdd(l + 3, e0.w);
        atomicAdd(l + 4, e1.x);
        atomicAdd(l + 5, e1.y);
        atomicAdd(l + 6, e1.z);
    }
    __syncthreads();
    float* dst = partials + ((size_t)b * SLICES + soff + s) * (PB * 7);
    for (int k = tid; k < PB * 7; k += 256) dst[k] = lacc[k];
}

// ---- fallback: direct global float atomics ----
__global__ void edge_kernel(const int* __restrict__ nbr,
                            const float* __restrict__ rad,
                            const float2* __restrict__ dirs,
                            const float4* __restrict__ pre2,
                            const float* __restrict__ supp,
                            const float* __restrict__ dtp,
                            float* __restrict__ acc, int E) {
    int e = blockIdx.x * blockDim.x + threadIdx.x;
    if (e >= E) return;
    int i; float4 c0, c1;
    edge_math2(nbr, rad, dirs, pre2, supp[0], dtp[0], e, E, i, c0, c1);
    float* base = acc + (size_t)i * 8;
    atomicAdd(base + 0, c0.x);
    atomicAdd(base + 1, c0.y);
    atomicAdd(base + 2, c0.z);
    atomicAdd(base + 3, c0.w);
    atomicAdd(base + 4, c1.x);
    atomicAdd(base + 5, c1.y);
    atomicAdd(base + 6, c1.z);
}

__global__ __launch_bounds__(256) void fin_kernel(
    const float* __restrict__ area,
    const float* __restrict__ actualArea,
    const float* __restrict__ restDensity,
    const float* __restrict__ dtp,
    const float* __restrict__ data, int mode,
    float* __restrict__ out, int n) {
    int t = blockIdx.x * blockDim.x + threadIdx.x;
    if (t >= n) return;
    float s0 = 0, s1 = 0, s2 = 0, s3 = 0, s4 = 0, s5 = 0, s6 = 0;
    if (mode == 0) {
        const float* base = data + ((size_t)(t >> PB_SHIFT) * SLICES) * (PB * 7)
                                 + (size_t)(t & (PB - 1)) * 7;
#pragma unroll
        for (int s = 0; s < SLICES; ++s) {
            const float* p = base + (size_t)s * (PB * 7);
            s0 += p[0]; s1 += p[1]; s2 += p[2]; s3 += p[3];
            s4 += p[4]; s5 += p[5]; s6 += p[6];
        }
    } else {
        const float* a = data + (size_t)t * 8;
        s0 = a[0]; s1 = a[1]; s2 = a[2]; s3 = a[3];
        s4 = a[4]; s5 = a[5]; s6 = a[6];
    }
    float dt   = dtp[0];
    float fac  = -dt * dt * actualArea[t];
    float mass = area[t] * restDensity[t];
    float alpha = fac / mass * (s0 * s0 + s1 * s1) + fac * s2;
    float* o = out + (size_t)t * 5;
    o[0] = alpha;
    o[1] = s3;
    o[2] = s4;
    o[3] = s5;
    o[4] = s6;
}

extern "C" void kernel_launch(void* const* d_in, const int* in_sizes, int n_in,
                              void* d_out, int out_size, void* d_ws, size_t ws_size,
                              hipStream_t stream) {
    const float* area        = (const float*)d_in[0];
    const float* actualArea  = (const float*)d_in[1];
    const float* restDensity = (const float*)d_in[2];
    const float* density     = (const float*)d_in[3];
    const float* pressure2   = (const float*)d_in[4];
    const float2* vel        = (const float2*)d_in[5];
    const float2* accel      = (const float2*)d_in[6];
    const float* rad         = (const float*)d_in[7];
    const float2* dirs       = (const float2*)d_in[8];
    const int*   nbr         = (const int*)d_in[9];
    const float* supp        = (const float*)d_in[10];
    const float* dtp         = (const float*)d_in[11];
    float* out = (float*)d_out;

    int N = in_sizes[0];
    int E = in_sizes[7];
    int nb = (N + PB - 1) >> PB_SHIFT;   // 128 for N=262144

    size_t sz_cur   = (size_t)nb * CSTRIDE * 8 * sizeof(int);  // up to 8 chunks
    size_t off_pre  = align256(sz_cur);
    size_t sz_pre   = (size_t)N * 8 * sizeof(float);
    size_t off_part = align256(off_pre + sz_pre);
    size_t sz_part  = (size_t)nb * SLICES * PB * 7 * sizeof(float);
    size_t off_pay  = align256(off_part + sz_part);

    int* cursor     = (int*)d_ws;
    float4* pre2    = (float4*)((char*)d_ws + off_pre);
    float* partials = (float*)((char*)d_ws + off_part);
    float4* payload = (float4*)((char*)d_ws + off_pay);

    // pick chunking so payload fits (entries are 32B, grouped by bucket)
    int nchunk = 0, cap = 0;
    if (nb <= 512 && ws_size > off_pay) {
        long long avail = (long long)ws_size - (long long)off_pay;
        for (int c = 1; c <= 8; c *= 2) {
            long long Ec = (E + c - 1) / c;
            double mean = (double)Ec / (double)nb;
            long long need = (long long)(mean + 8.0 * sqrt(mean) + 256.0);
            need = (need + 7) & ~7ll;
            if ((long long)nb * need * 32ll <= avail) { nchunk = c; cap = (int)need; break; }
        }
    }

    int bs = 256;
    if (nchunk > 0) {
        int ncursor = nb * CSTRIDE * nchunk;
        int grid_n  = (N + bs - 1) / bs;
        pre_kernel<<<grid_n, bs, 0, stream>>>(
            area, actualArea, restDensity, density, pressure2, vel, accel,
            pre2, cursor, ncursor, (float*)nullptr, 0, N);
        int spc = SLICES / nchunk;
        int Ec  = (E + nchunk - 1) / nchunk;
        for (int c = 0; c < nchunk; ++c) {
            int es = c * Ec;
            int ee = es + Ec; if (ee > E) ee = E;
            if (es >= ee) break;
            int* curC = cursor + (size_t)c * nb * CSTRIDE;
            int nblk = (ee - es + 256 * EPT - 1) / (256 * EPT);
            bin_kernel<<<nblk, bs, 0, stream>>>(
                nbr, rad, dirs, pre2, supp, dtp, curC, payload, cap, nb, es, ee, E);
            reduce_kernel<<<nb * spc, bs, 0, stream>>>(
                payload, curC, cap, partials, spc, c * spc);
        }
        fin_kernel<<<grid_n, bs, 0, stream>>>(
            area, actualArea, restDensity, dtp, partials, 0, out, N);
    } else {
        // fallback: direct atomics into acc[N,8] placed at off_part
        float* acc = partials;
        int grid_n = (N + bs - 1) / bs;
        pre_kernel<<<grid_n, bs, 0, stream>>>(
            area, actualArea, restDensity, density, pressure2, vel, accel,
            pre2, cursor, 0, acc, N * 8, N);
        edge_kernel<<<(E + bs - 1) / bs, bs, 0, stream>>>(
            nbr, rad, dirs, pre2, supp, dtp, acc, E);
        fin_kernel<<<grid_n, bs, 0, stream>>>(
            area, actualArea, restDensity, dtp, acc, 1, out, N);
    }
}